// Round 1
// baseline (381.889 us; speedup 1.0000x reference)
//
#include <hip/hip_runtime.h>
#include <math.h>

// Problem constants
#define C_IN   2048
#define HID    9
#define NIDX   4096          // 2048 pos + 2048 neg
#define WT_STRIDE 108        // per-channel transposed weights: 9 taps * 12 (pad for float4)

// conv_gather config
#define CW   16              // channel ways (channels per sub-chunk)
#define EGN  16              // entry groups
#define ENT  12              // entry slots per thread -> capacity 192 per image
#define CAP  (EGN*ENT)
#define LCAP 512

// ---------------------------------------------------------------------------
// P0: transpose Wh [9][2048][3][3] -> Wt [2048][9 taps][12 pad] (oc innermost),
//     and zero the x accumulator (ws is poisoned before every launch).
// ---------------------------------------------------------------------------
__global__ void prep_kernel(const float* __restrict__ Wh,
                            float* __restrict__ Wt,
                            float* __restrict__ x) {
  int e = blockIdx.x * 256 + threadIdx.x;     // grid covers exactly 9*2048*9 = 165888
  if (e < HID * C_IN * 9) {
    int oc  = e / (C_IN * 9);
    int rem = e - oc * (C_IN * 9);
    int c   = rem / 9;
    int tap = rem - c * 9;
    Wt[c * WT_STRIDE + tap * 12 + oc] = Wh[e];
  }
  if (e < NIDX * HID) x[e] = 0.f;
}

// ---------------------------------------------------------------------------
// P1: sparse conv1 at gathered positions, streaming the feature map densely.
// grid = (32 channel-chunks, 32 images), 256 threads.
// ---------------------------------------------------------------------------
__global__ __launch_bounds__(256, 2) void conv_gather(
    const float* __restrict__ feat,
    const int*   __restrict__ pos_idx,
    const int*   __restrict__ neg_idx,
    const float* __restrict__ Wt,
    float*       __restrict__ x) {
  __shared__ __align__(16) float limg[CW * 729];   // 16 ch x 27x27 zero-halo
  __shared__ __align__(16) float lw[CW * WT_STRIDE];
  __shared__ unsigned short lp27[LCAP];
  __shared__ unsigned short lslot[LCAP];
  __shared__ int lcnt;

  const int t     = threadIdx.x;
  const int chunk = blockIdx.x;   // 0..31, 64 channels each
  const int b     = blockIdx.y;   // image

  if (t == 0) lcnt = 0;
  // zero whole halo image once; interiors get overwritten each sub-chunk,
  // borders stay zero forever.
  for (int i = t; i < CW * 729; i += 256) limg[i] = 0.f;
  __syncthreads();

  // Compact this image's entries into LDS. flat = ((b*25+h)*25+w)*9 + anc.
  for (int i = t; i < NIDX; i += 256) {
    int flat = (i < 2048) ? pos_idx[i] : neg_idx[i - 2048];
    int pw = flat / 9;            // b*625 + h*25 + w
    int bb = pw / 625;
    if (bb == b) {
      int p = pw - bb * 625;
      int n = atomicAdd(&lcnt, 1);
      if (n < LCAP) {
        int h = p / 25, w = p - h * 25;
        lp27[n]  = (unsigned short)((h + 1) * 27 + (w + 1));
        lslot[n] = (unsigned short)i;
      }
    }
  }
  __syncthreads();
  const int Nb = min(lcnt, LCAP);

  const int cw = t & 15;          // channel way within sub-chunk
  const int eg = t >> 4;          // entry group

  int p27[ENT];
#pragma unroll
  for (int r = 0; r < ENT; r++) {
    int e = eg + EGN * r;
    p27[r] = (e < Nb) ? (int)lp27[e] : 28;   // 28 = safe in-bounds center
  }

  float acc[ENT][9];
#pragma unroll
  for (int r = 0; r < ENT; r++)
#pragma unroll
    for (int o = 0; o < 9; o++) acc[r][o] = 0.f;

  const float* gsrc = feat + (size_t)(b * C_IN + chunk * 64) * 625;
  const float* wsrc = Wt + (size_t)(chunk * 64) * WT_STRIDE;

  for (int s = 0; s < 4; s++) {               // 4 sub-chunks of 16 channels
    __syncthreads();                          // prev compute done before restage
    // stage 16 ch x 625 floats = 2500 float4 (16B-aligned: 16*625*4 = 40000)
    const float4* g4 = (const float4*)(gsrc + s * CW * 625);
    for (int i = t; i < 2500; i += 256) {
      float4 v = g4[i];
      int f = i * 4;
      float vv[4] = {v.x, v.y, v.z, v.w};
#pragma unroll
      for (int k = 0; k < 4; k++) {
        int ff = f + k;
        int c8 = ff / 625;
        int p  = ff - c8 * 625;
        int h = p / 25, w = p - h * 25;
        limg[c8 * 729 + (h + 1) * 27 + (w + 1)] = vv[k];
      }
    }
    // stage weights: 16 ch * 108 floats = 432 float4, contiguous
    const float4* w4 = (const float4*)(wsrc + s * CW * WT_STRIDE);
    float4* lw4 = (float4*)lw;
    for (int i = t; i < (CW * WT_STRIDE) / 4; i += 256) lw4[i] = w4[i];
    __syncthreads();

    const float* img = limg + cw * 729;
    const float* wr  = lw + cw * WT_STRIDE;
#pragma unroll
    for (int tap = 0; tap < 9; tap++) {
      const int toff = (tap / 3) * 27 + (tap % 3) - 28;
      float4 wa = *(const float4*)(wr + tap * 12);
      float4 wb = *(const float4*)(wr + tap * 12 + 4);
      float  w8 = wr[tap * 12 + 8];
#pragma unroll
      for (int r = 0; r < ENT; r++) {
        if (eg + EGN * r < Nb) {
          float v = img[p27[r] + toff];
          acc[r][0] += v * wa.x; acc[r][1] += v * wa.y; acc[r][2] += v * wa.z;
          acc[r][3] += v * wa.w; acc[r][4] += v * wb.x; acc[r][5] += v * wb.y;
          acc[r][6] += v * wb.z; acc[r][7] += v * wb.w; acc[r][8] += v * w8;
        }
      }
    }

    // Overflow safety (Nb > 192): statistically never taken, keeps correctness.
    if (Nb > CAP) {
      for (int e = CAP + eg; e < Nb; e += EGN) {
        int pp = lp27[e];
        float oacc[9] = {0, 0, 0, 0, 0, 0, 0, 0, 0};
#pragma unroll
        for (int tap = 0; tap < 9; tap++) {
          float v = img[pp + (tap / 3) * 27 + (tap % 3) - 28];
          const float* wrr = wr + tap * 12;
#pragma unroll
          for (int o = 0; o < 9; o++) oacc[o] += v * wrr[o];
        }
        int sl = lslot[e];
#pragma unroll
        for (int o = 0; o < 9; o++) atomicAdd(&x[sl * 9 + o], oacc[o]);
      }
    }
  }

  // Reduce partials across the 16 channel-way lanes (contiguous in wave),
  // one atomicAdd per (entry, oc) per block.
#pragma unroll
  for (int r = 0; r < ENT; r++) {
    int e = eg + EGN * r;
    if (e < Nb) {                 // uniform across the 16 lanes of this eg
      int sl = lslot[e];
#pragma unroll
      for (int o = 0; o < 9; o++) {
        float v = acc[r][o];
        v += __shfl_xor(v, 1);
        v += __shfl_xor(v, 2);
        v += __shfl_xor(v, 4);
        v += __shfl_xor(v, 8);
        if (cw == 0) atomicAdd(&x[sl * 9 + o], v);
      }
    }
  }
}

// ---------------------------------------------------------------------------
// P2: bias + ReLU + conf/offset heads + box transform. 4096 threads.
// out layout: [0,2048) pos_conf | [2048,4096) neg_conf |
//             [4096,12288) pos_offsets | [12288,20480) proposals
// ---------------------------------------------------------------------------
__global__ void heads_kernel(const float* __restrict__ x,
                             const int*   __restrict__ pos_idx,
                             const int*   __restrict__ neg_idx,
                             const float* __restrict__ pos_ancs,
                             const float* __restrict__ bh,
                             const float* __restrict__ Wc,
                             const float* __restrict__ bc,
                             const float* __restrict__ Wr,
                             const float* __restrict__ br,
                             float*       __restrict__ out) {
  int i = blockIdx.x * 256 + threadIdx.x;
  if (i >= NIDX) return;
  int flat = (i < 2048) ? pos_idx[i] : neg_idx[i - 2048];
  int anc = flat % 9;
  float xr[9];
#pragma unroll
  for (int j = 0; j < 9; j++) {
    float v = x[i * 9 + j] + bh[j];
    xr[j] = v > 0.f ? v : 0.f;
  }
  float conf = bc[anc];
#pragma unroll
  for (int j = 0; j < 9; j++) conf += xr[j] * Wc[anc * 9 + j];
  out[i] = conf;
  if (i < 2048) {
    float off[4];
#pragma unroll
    for (int k = 0; k < 4; k++) {
      float sacc = br[anc * 4 + k];
#pragma unroll
      for (int j = 0; j < 9; j++) sacc += xr[j] * Wr[(anc * 4 + k) * 9 + j];
      off[k] = sacc;
      out[4096 + i * 4 + k] = sacc;
    }
    float x1 = pos_ancs[i * 4 + 0], y1 = pos_ancs[i * 4 + 1];
    float x2 = pos_ancs[i * 4 + 2], y2 = pos_ancs[i * 4 + 3];
    float cx = (x1 + x2) * 0.5f, cy = (y1 + y2) * 0.5f;
    float w = x2 - x1, h = y2 - y1;
    float ncx = cx + off[0] * w, ncy = cy + off[1] * h;
    float nw = w * expf(off[2]), nh = h * expf(off[3]);
    out[12288 + i * 4 + 0] = ncx - nw * 0.5f;
    out[12288 + i * 4 + 1] = ncy - nh * 0.5f;
    out[12288 + i * 4 + 2] = ncx + nw * 0.5f;
    out[12288 + i * 4 + 3] = ncy + nh * 0.5f;
  }
}

// ---------------------------------------------------------------------------
extern "C" void kernel_launch(void* const* d_in, const int* in_sizes, int n_in,
                              void* d_out, int out_size, void* d_ws, size_t ws_size,
                              hipStream_t stream) {
  const float* feat     = (const float*)d_in[0];
  const int*   pos_idx  = (const int*)d_in[1];
  const int*   neg_idx  = (const int*)d_in[2];
  const float* pos_ancs = (const float*)d_in[3];
  const float* Wh       = (const float*)d_in[4];
  const float* bh       = (const float*)d_in[5];
  const float* Wc       = (const float*)d_in[6];
  const float* bc       = (const float*)d_in[7];
  const float* Wr       = (const float*)d_in[8];
  const float* br       = (const float*)d_in[9];
  float* out = (float*)d_out;

  float* Wt = (float*)d_ws;                       // 2048*108 floats = 884736 B
  float* x  = Wt + (size_t)C_IN * WT_STRIDE;      // 4096*9 floats   = 147456 B

  prep_kernel<<<648, 256, 0, stream>>>(Wh, Wt, x);
  conv_gather<<<dim3(32, 32), 256, 0, stream>>>(feat, pos_idx, neg_idx, Wt, x);
  heads_kernel<<<16, 256, 0, stream>>>(x, pos_idx, neg_idx, pos_ancs,
                                       bh, Wc, bc, Wr, br, out);
}